// Round 5
// baseline (615.039 us; speedup 1.0000x reference)
//
#include <hip/hip_runtime.h>

#define S_LEN 2048
#define DIM   4096
#define NH    32
#define NKV   8
#define HD    128
#define QKV_LD 6144          // fused qkv row: [q 4096 | k 1024 | v 1024]
#define KOFF 4096
#define VOFF 5120

typedef __attribute__((ext_vector_type(8))) __bf16 bf16x8;
typedef __attribute__((ext_vector_type(4))) float  floatx4;

union U8 { unsigned short u[8]; bf16x8 v; int4 i4; };
union U32x4 { unsigned int u[4]; bf16x8 v; };

__device__ inline unsigned short f2bf(float f) {
  unsigned int u = __float_as_uint(f);
  u += 0x7fff + ((u >> 16) & 1);          // round-to-nearest-even
  return (unsigned short)(u >> 16);
}
__device__ inline float bf2f(unsigned short h) {
  return __uint_as_float(((unsigned int)h) << 16);
}

__device__ inline floatx4 mfma16(bf16x8 a, bf16x8 b, floatx4 c) {
  return __builtin_amdgcn_mfma_f32_16x16x32_bf16(a, b, c, 0, 0, 0);
}

// async global->LDS, 16B per lane. lds dest = wave-uniform base + lane*16;
// global src address is PER-LANE (enables pre-swizzled sources, m173).
typedef __attribute__((address_space(1))) void GV;
typedef __attribute__((address_space(3))) void LV;
__device__ inline void gload_lds16(const unsigned short* g, unsigned short* l) {
  __builtin_amdgcn_global_load_lds((GV*)g, (LV*)l, 16, 0, 0);
}

template<int N> __device__ __forceinline__ void vmcnt_wait() {
  if constexpr (N == 8)      asm volatile("s_waitcnt vmcnt(8)" ::: "memory");
  else if constexpr (N == 6) asm volatile("s_waitcnt vmcnt(6)" ::: "memory");
  else if constexpr (N == 4) asm volatile("s_waitcnt vmcnt(4)" ::: "memory");
  else if constexpr (N == 3) asm volatile("s_waitcnt vmcnt(3)" ::: "memory");
  else                       asm volatile("s_waitcnt vmcnt(0)" ::: "memory");
}

// ---------------------------------------------------------------------------
// fp32 [K][N] -> bf16 [N][K] transpose+convert (32x32 tiles via LDS).
// ---------------------------------------------------------------------------
__global__ __launch_bounds__(256) void transpose_cvt(
    const float* __restrict__ in, unsigned short* __restrict__ outT, int K, int N)
{
  __shared__ float t[32][33];
  const int n0 = blockIdx.x * 32, k0 = blockIdx.y * 32;
  const int tx = threadIdx.x & 31, ty = threadIdx.x >> 5;   // ty 0..7
#pragma unroll
  for (int i = 0; i < 32; i += 8)
    t[ty + i][tx] = in[(size_t)(k0 + ty + i) * N + n0 + tx];
  __syncthreads();
#pragma unroll
  for (int i = 0; i < 32; i += 8)
    outT[(size_t)(n0 + ty + i) * K + k0 + tx] = f2bf(t[tx][ty + i]);
}

// ---------------------------------------------------------------------------
// fp32 -> bf16 elementwise (8 el/thread).
// ---------------------------------------------------------------------------
__global__ __launch_bounds__(256) void cvt_f32_bf16(
    const float* __restrict__ in, unsigned short* __restrict__ out)
{
  int i = (blockIdx.x * 256 + threadIdx.x) * 8;
  float4 a = *(const float4*)(in + i);
  float4 b = *(const float4*)(in + i + 4);
  U8 t;
  t.u[0] = f2bf(a.x); t.u[1] = f2bf(a.y); t.u[2] = f2bf(a.z); t.u[3] = f2bf(a.w);
  t.u[4] = f2bf(b.x); t.u[5] = f2bf(b.y); t.u[6] = f2bf(b.z); t.u[7] = f2bf(b.w);
  *(int4*)(out + i) = t.i4;
}

// ---------------------------------------------------------------------------
// Deep-pipelined GEMM (T2+T3/T4+T5): A [M][K] bf16, Bt [N][K] bf16, C [M][N].
// 8 waves (512 thr) as WM x WN; per-wave tile (BM/WM) x (BN/WN).
// K pipelined in 32-wide slabs through a 4-deep circular LDS buffer:
//   iter t: stage slab t+3 (gload_lds, pre-swizzled global src) |
//           ds_read slab t | 32 MFMA | vmcnt(2L) | lgkmcnt(0) | s_barrier.
// Sync invariants:
//  - buf[(t+3)&3] was last ds_read at slab t-1; those reads complete before
//    the t-1 barrier (lgkmcnt before barrier) -> staging at iter t is race-free.
//  - vmcnt(2L) leaves slabs t+2,t+3 in flight but guarantees t+1 landed
//    before the barrier that precedes its reads. Tail drains 2L -> L -> 0.
// LDS chunk swizzle: 16B-chunk cir ^= (row>>1)&3 (write side folded into the
// global source address; read side applied to the ds_read addr) -> 2-way
// bank aliasing (free) instead of ~8-way.
// ---------------------------------------------------------------------------
template<int BM, int BN, int WM, int WN, bool C_F32>
__global__ __launch_bounds__(512, 2) void gemm_pipe(
    const unsigned short* __restrict__ A,
    const unsigned short* __restrict__ Bt,
    void* __restrict__ C_, int M, int N, int K)
{
  constexpr int MFRAG = BM / WM / 16;
  constexpr int NFRAG = BN / WN / 16;
  constexpr int LA = BM / 128;              // gload_lds per wave per A-slab
  constexpr int LB = BN / 128;
  constexpr int L  = LA + LB;

  __shared__ __align__(16) unsigned short As[4][BM * 32];
  __shared__ __align__(16) unsigned short Bs[4][BN * 32];

  // XCD-bijective block swizzle (grid % 8 == 0 for all our launches).
  const int nwg  = gridDim.x * gridDim.y;
  const int bid0 = blockIdx.y * gridDim.x + blockIdx.x;
  const int wg   = (bid0 & 7) * (nwg >> 3) + (bid0 >> 3);
  const int bx = wg % gridDim.x, by = wg / gridDim.x;
  const int m0 = by * BM, n0 = bx * BN;

  const int tid  = threadIdx.x;
  const int wave = tid >> 6, lane = tid & 63;
  const int quad = lane >> 4, l16 = lane & 15;
  const int wm = wave / WN, wn = wave % WN;
  const int nslab = K >> 5;

#define STAGE(t_) do {                                                          \
    int b_ = (t_) & 3; int k0_ = (t_) * 32;                                     \
    _Pragma("unroll")                                                           \
    for (int s = 0; s < LA; s++) {                                              \
      int c = s * 512 + wave * 64 + lane;                                       \
      int row = c >> 2, cir = (c & 3) ^ ((row >> 1) & 3);                       \
      gload_lds16(A + (size_t)(m0 + row) * K + k0_ + cir * 8,                   \
                  &As[b_][(s * 512 + wave * 64) * 8]);                          \
    }                                                                           \
    _Pragma("unroll")                                                           \
    for (int s = 0; s < LB; s++) {                                              \
      int c = s * 512 + wave * 64 + lane;                                       \
      int row = c >> 2, cir = (c & 3) ^ ((row >> 1) & 3);                       \
      gload_lds16(Bt + (size_t)(n0 + row) * K + k0_ + cir * 8,                  \
                  &Bs[b_][(s * 512 + wave * 64) * 8]);                          \
    } } while (0)

  floatx4 acc[MFRAG][NFRAG] = {};

  STAGE(0); STAGE(1); STAGE(2);
  vmcnt_wait<2 * L>();                       // slab 0 landed
  __builtin_amdgcn_s_barrier();
  __builtin_amdgcn_sched_barrier(0);

  for (int t = 0; t < nslab; t++) {
    if (t + 3 < nslab) STAGE(t + 3);

    const unsigned short* Ab = As[t & 3];
    const unsigned short* Bb = Bs[t & 3];
    bf16x8 af[MFRAG], bf[NFRAG];
#pragma unroll
    for (int m = 0; m < MFRAG; m++) {
      int row = wm * (MFRAG * 16) + m * 16 + l16;
      af[m] = *(const bf16x8*)(Ab + row * 32 + (quad ^ ((row >> 1) & 3)) * 8);
    }
#pragma unroll
    for (int n = 0; n < NFRAG; n++) {
      int row = wn * (NFRAG * 16) + n * 16 + l16;
      bf[n] = *(const bf16x8*)(Bb + row * 32 + (quad ^ ((row >> 1) & 3)) * 8);
    }

    __builtin_amdgcn_s_setprio(1);
#pragma unroll
    for (int m = 0; m < MFRAG; m++)
#pragma unroll
      for (int n = 0; n < NFRAG; n++)
        acc[m][n] = mfma16(af[m], bf[n], acc[m][n]);
    __builtin_amdgcn_s_setprio(0);

    if (t + 3 < nslab)      vmcnt_wait<2 * L>();   // t+1 landed, 2 slabs fly
    else if (t + 2 < nslab) vmcnt_wait<L>();       // tail: only t+2 in flight
    else if (t + 1 < nslab) vmcnt_wait<0>();       // tail: t+1 must land
    asm volatile("s_waitcnt lgkmcnt(0)" ::: "memory");  // my reads of buf done
    __builtin_amdgcn_s_barrier();
    __builtin_amdgcn_sched_barrier(0);
  }
#undef STAGE

#pragma unroll
  for (int m = 0; m < MFRAG; m++)
#pragma unroll
    for (int n = 0; n < NFRAG; n++)
#pragma unroll
      for (int i = 0; i < 4; i++) {
        int r = m0 + wm * (MFRAG * 16) + m * 16 + quad * 4 + i;
        int c = n0 + wn * (NFRAG * 16) + n * 16 + l16;
        if (C_F32) ((float*)C_)[(size_t)r * N + c] = acc[m][n][i];
        else ((unsigned short*)C_)[(size_t)r * N + c] = f2bf(acc[m][n][i]);
      }
}

// ---------------------------------------------------------------------------
// RoPE in-place on fused qkv [S][6144]: q cols scaled by 1/sqrt(HD) (folds the
// attention scale), k cols unscaled. cos/sin fp32 [s][p].
// ---------------------------------------------------------------------------
__global__ __launch_bounds__(256) void rope_kernel(
    unsigned short* __restrict__ qkv,
    const float* __restrict__ fcos, const float* __restrict__ fsin)
{
  int idx = blockIdx.x * 256 + threadIdx.x;   // S_LEN*(NH+NKV)*64 threads
  int p = idx & 63;
  int t = idx >> 6;
  int h = t % (NH + NKV);
  int s = t / (NH + NKV);

  float c  = fcos[s * 64 + p];
  float sn = fsin[s * 64 + p];
  const float qs = 0.08838834764831845f;      // 1/sqrt(128)

  unsigned short* base;
  float m;
  if (h < NH) { base = qkv + (size_t)s * QKV_LD + h * HD + p * 2; m = qs; }
  else { base = qkv + (size_t)s * QKV_LD + KOFF + (h - NH) * HD + p * 2; m = 1.f; }

  unsigned int both = *(const unsigned int*)base;
  float t0 = bf2f((unsigned short)(both & 0xffff));
  float t1 = bf2f((unsigned short)(both >> 16));
  unsigned int o0 = f2bf((t0 * c - t1 * sn) * m);
  unsigned int o1 = f2bf((t0 * sn + t1 * c) * m);
  *(unsigned int*)base = o0 | (o1 << 16);
}

// ---------------------------------------------------------------------------
// V transpose: vt[kv*HD + d][s] = qkv[s][VOFF + kv*HD + d]. (bf16)
// 32x32 LDS-tiled so both sides are coalesced.
// ---------------------------------------------------------------------------
__global__ __launch_bounds__(256) void vtrans_kernel(
    const unsigned short* __restrict__ qkv, unsigned short* __restrict__ vt)
{
  __shared__ unsigned short t[32][34];
  const int s0 = blockIdx.x * 32;                  // S_LEN/32 blocks
  const int d0 = blockIdx.y * 32;                  // (NKV*HD)/32 blocks
  const int tx = threadIdx.x & 31, ty = threadIdx.x >> 5;   // ty 0..7
#pragma unroll
  for (int i = 0; i < 32; i += 8)
    t[ty + i][tx] = qkv[(size_t)(s0 + ty + i) * QKV_LD + VOFF + d0 + tx];
  __syncthreads();
#pragma unroll
  for (int i = 0; i < 32; i += 8)
    vt[(size_t)(d0 + ty + i) * S_LEN + s0 + tx] = t[tx][ty + i];
}

// ---------------------------------------------------------------------------
// Flash attention, no-max softmax. Swapped QK^T (mfma(K,Q)) -> P lane-local,
// softmax in-register, PV A-frag via cross-quad shfl. Double-buffered K/V,
// one barrier per KV-iteration. Grid (NH, S/128); 4 waves; 2 blocks/CU.
// (verified round 3: 567 us total, attn no longer in top-5)
// ---------------------------------------------------------------------------
__global__ __launch_bounds__(256, 2) void attn_kernel(
    const unsigned short* __restrict__ qkv,
    const unsigned short* __restrict__ vt,
    unsigned short* __restrict__ o)
{
  __shared__ __align__(16) unsigned short Ks[2][64 * 136];
  __shared__ __align__(16) unsigned short Vs[2][128 * 72];

  const int h    = blockIdx.x;
  const int qblk = blockIdx.y;
  const int kvh  = h >> 2;
  const int tid  = threadIdx.x;
  const int lane = tid & 63;
  const int quad = lane >> 4;
  const int l16  = lane & 15;
  const int wave = tid >> 6;
  const int qr   = qblk * 128 + wave * 16;        // + mt*64

  bf16x8 qf[2][4];
#pragma unroll
  for (int mt = 0; mt < 2; mt++)
#pragma unroll
    for (int ks = 0; ks < 4; ks++)
      qf[mt][ks] = *(const bf16x8*)(qkv + (size_t)(qr + mt * 64 + l16) * QKV_LD
                                    + h * HD + ks * 32 + quad * 8);

  floatx4 accO[2][8] = {};
  float l_i[2] = {0.f, 0.f};

  int4 pk[4], pv4[4];
#define LOAD_TILE(kb_) do {                                                     \
    _Pragma("unroll")                                                           \
    for (int j = 0; j < 4; j++) {                                               \
      int c = tid + 256 * j;                                                    \
      pk[j] = *(const int4*)(qkv + (size_t)((kb_) * 64 + (c >> 4)) * QKV_LD     \
                              + KOFF + kvh * HD + (c & 15) * 8);                \
      pv4[j] = *(const int4*)(vt + (size_t)(kvh * HD + (c >> 3)) * S_LEN        \
                              + (kb_) * 64 + (c & 7) * 8);                      \
    } } while (0)
#define STORE_TILE(b_) do {                                                     \
    _Pragma("unroll")                                                           \
    for (int j = 0; j < 4; j++) {                                               \
      int c = tid + 256 * j;                                                    \
      *(int4*)(Ks[b_] + (c >> 4) * 136 + (c & 15) * 8) = pk[j];                 \
      *(int4*)(Vs[b_] + (c >> 3) * 72 + (c & 7) * 8) = pv4[j];                  \
    } } while (0)

  LOAD_TILE(0);
  STORE_TILE(0);
  __syncthreads();

  const int srcA = ((quad & 1) << 5) | l16;       // quad-pair source lane
  const bool hi  = (quad & 2);                    // nt = 2*k2 + (quad>>1)

  for (int kb = 0; kb < S_LEN / 64; kb++) {
    const int cur = kb & 1;
    if (kb + 1 < S_LEN / 64) LOAD_TILE(kb + 1);   // global->reg, spans compute

    const unsigned short* Ksc = Ks[cur];
    const unsigned short* Vsc = Vs[cur];

    // ---- S^T = K Q^T : lane holds P-row slice for q=l16 ----
    floatx4 sacc[2][4] = {};
    __builtin_amdgcn_s_setprio(1);
#pragma unroll
    for (int ks = 0; ks < 4; ks++)
#pragma unroll
      for (int nt = 0; nt < 4; nt++) {
        bf16x8 kf = *(const bf16x8*)(Ksc + (nt * 16 + l16) * 136 + ks * 32 + quad * 8);
        sacc[0][nt] = mfma16(kf, qf[0][ks], sacc[0][nt]);
        sacc[1][nt] = mfma16(kf, qf[1][ks], sacc[1][nt]);
      }
    __builtin_amdgcn_s_setprio(0);

    // ---- P = exp(S); per-lane l partial; pack to bf16 words in-register ----
    unsigned int wp[2][2][4];   // [mt][word 0/1][nt]
#pragma unroll
    for (int mt = 0; mt < 2; mt++) {
      float ls = 0.f;
#pragma unroll
      for (int nt = 0; nt < 4; nt++) {
        float e0 = __expf(sacc[mt][nt][0]);
        float e1 = __expf(sacc[mt][nt][1]);
        float e2 = __expf(sacc[mt][nt][2]);
        float e3 = __expf(sacc[mt][nt][3]);
        ls += (e0 + e1) + (e2 + e3);
        wp[mt][0][nt] = (unsigned int)f2bf(e0) | ((unsigned int)f2bf(e1) << 16);
        wp[mt][1][nt] = (unsigned int)f2bf(e2) | ((unsigned int)f2bf(e3) << 16);
      }
      l_i[mt] += ls;
    }

    // ---- O += P V ; A-fragment via cross-quad exchange ----
#pragma unroll
    for (int k2 = 0; k2 < 2; k2++) {
      bf16x8 paf[2];
#pragma unroll
      for (int mt = 0; mt < 2; mt++) {
        const int ntl = k2 * 2, nth = k2 * 2 + 1;
        unsigned int a0 = __shfl((int)wp[mt][0][ntl], srcA, 64);
        unsigned int b0 = __shfl((int)wp[mt][0][nth], srcA, 64);
        unsigned int a1 = __shfl((int)wp[mt][1][ntl], srcA, 64);
        unsigned int b1 = __shfl((int)wp[mt][1][nth], srcA, 64);
        unsigned int a2 = __shfl((int)wp[mt][0][ntl], srcA + 16, 64);
        unsigned int b2 = __shfl((int)wp[mt][0][nth], srcA + 16, 64);
        unsigned int a3 = __shfl((int)wp[mt][1][ntl], srcA + 16, 64);
        unsigned int b3 = __shfl((int)wp[mt][1][nth], srcA + 16, 64);
        U32x4 pw;
        pw.u[0] = hi ? b0 : a0;
        pw.u[1] = hi ? b1 : a1;
        pw.u[2] = hi ? b2 : a2;
        pw.u[3] = hi ? b3 : a3;
        paf[mt] = pw.v;
      }
      __builtin_amdgcn_s_setprio(1);
#pragma unroll
      for (int dt = 0; dt < 8; dt++) {
        bf16x8 vf = *(const bf16x8*)(Vsc + (dt * 16 + l16) * 72 + k2 * 32 + quad * 8);
        accO[0][dt] = mfma16(paf[0], vf, accO[0][dt]);
        accO[1][dt] = mfma16(paf[1], vf, accO[1][dt]);
      }
      __builtin_amdgcn_s_setprio(0);
    }

    if (kb + 1 < S_LEN / 64) STORE_TILE(cur ^ 1);   // buf was drained last iter
    __syncthreads();
  }

  // ---- l: sum the 4 quad partials for each q=l16; broadcast to output rows --
#pragma unroll
  for (int mt = 0; mt < 2; mt++) {
    l_i[mt] += __shfl_xor(l_i[mt], 16, 64);
    l_i[mt] += __shfl_xor(l_i[mt], 32, 64);
  }

#pragma unroll
  for (int mt = 0; mt < 2; mt++) {
    float lq[4];
#pragma unroll
    for (int i = 0; i < 4; i++) lq[i] = __shfl(l_i[mt], quad * 4 + i, 64);
#pragma unroll
    for (int dt = 0; dt < 8; dt++)
#pragma unroll
      for (int i = 0; i < 4; i++) {
        float val = accO[mt][dt][i] / lq[i];
        o[(size_t)(qr + mt * 64 + quad * 4 + i) * (NH * HD) + h * HD + dt * 16 + l16]
            = f2bf(val);
      }
  }
#undef LOAD_TILE
#undef STORE_TILE
}

// ---------------------------------------------------------------------------
extern "C" void kernel_launch(void* const* d_in, const int* in_sizes, int n_in,
                              void* d_out, int out_size, void* d_ws, size_t ws_size,
                              hipStream_t stream)
{
  const float* x    = (const float*)d_in[0];
  const float* fcos = (const float*)d_in[1];
  const float* fsin = (const float*)d_in[2];
  const float* wq   = (const float*)d_in[3];
  const float* wk   = (const float*)d_in[4];
  const float* wv   = (const float*)d_in[5];
  const float* wo   = (const float*)d_in[6];
  float* out = (float*)d_out;

  unsigned short* ws = (unsigned short*)d_ws;
  unsigned short* xb   = ws;                                   // S*DIM
  unsigned short* wT   = xb   + (size_t)S_LEN * DIM;           // [6144][4096]
  unsigned short* woT  = wT   + (size_t)QKV_LD * DIM;          // [4096][4096]
  unsigned short* qkv  = woT  + (size_t)DIM * (NH * HD);       // [S][6144]
  unsigned short* vt   = qkv  + (size_t)S_LEN * QKV_LD;        // [NKV][HD][S]
  unsigned short* attn = vt   + (size_t)S_LEN * (NKV * HD);    // [S][4096]
  // total ~146 MB of d_ws

  // one-time per launch: x -> bf16; weights -> bf16 [N][K], q|k|v contiguous
  cvt_f32_bf16<<<(S_LEN * DIM) / (256 * 8), 256, 0, stream>>>(x, xb);
  transpose_cvt<<<dim3(DIM / 32, DIM / 32),        256, 0, stream>>>(wq, wT, DIM, DIM);
  transpose_cvt<<<dim3((NKV * HD) / 32, DIM / 32), 256, 0, stream>>>(wk, wT + (size_t)KOFF * DIM, DIM, NKV * HD);
  transpose_cvt<<<dim3((NKV * HD) / 32, DIM / 32), 256, 0, stream>>>(wv, wT + (size_t)VOFF * DIM, DIM, NKV * HD);
  transpose_cvt<<<dim3(DIM / 32, (NH * HD) / 32),  256, 0, stream>>>(wo, woT, NH * HD, DIM);

  // fused QKV projection: [S][6144], 256x256 tiles -> 192 blocks (1 round)
  gemm_pipe<256, 256, 2, 4, false>
      <<<dim3(QKV_LD / 256, S_LEN / 256), 512, 0, stream>>>(xb, wT, qkv, S_LEN, QKV_LD, DIM);

  rope_kernel<<<(S_LEN * (NH + NKV) * 64) / 256, 256, 0, stream>>>(qkv, fcos, fsin);
  vtrans_kernel<<<dim3(S_LEN / 32, (NKV * HD) / 32), 256, 0, stream>>>(qkv, vt);

  attn_kernel<<<dim3(NH, S_LEN / 128), 256, 0, stream>>>(qkv, vt, attn);

  // output projection -> fp32 d_out, 128x256 tiles -> exactly 256 blocks
  gemm_pipe<128, 256, 2, 4, true>
      <<<dim3(DIM / 256, S_LEN / 128), 512, 0, stream>>>(attn, woT, out, S_LEN, DIM, NH * HD);
}

// Round 6
// 567.316 us; speedup vs baseline: 1.0841x; 1.0841x over previous
//
#include <hip/hip_runtime.h>

#define S_LEN 2048
#define DIM   4096
#define NH    32
#define NKV   8
#define HD    128
#define QKV_LD 6144          // fused qkv row: [q 4096 | k 1024 | v 1024]
#define KOFF 4096
#define VOFF 5120

typedef __attribute__((ext_vector_type(8))) __bf16 bf16x8;
typedef __attribute__((ext_vector_type(4))) float  floatx4;

union U8 { unsigned short u[8]; bf16x8 v; int4 i4; };
union U32x4 { unsigned int u[4]; bf16x8 v; };

__device__ inline unsigned short f2bf(float f) {
  unsigned int u = __float_as_uint(f);
  u += 0x7fff + ((u >> 16) & 1);          // round-to-nearest-even
  return (unsigned short)(u >> 16);
}
__device__ inline float bf2f(unsigned short h) {
  return __uint_as_float(((unsigned int)h) << 16);
}

__device__ inline floatx4 mfma16(bf16x8 a, bf16x8 b, floatx4 c) {
  return __builtin_amdgcn_mfma_f32_16x16x32_bf16(a, b, c, 0, 0, 0);
}

// async global->LDS, 16B per lane. lds dest = wave-uniform base + lane*16;
// global src address is PER-LANE (enables pre-swizzled sources, m173).
typedef __attribute__((address_space(1))) void GV;
typedef __attribute__((address_space(3))) void LV;
__device__ inline void gload_lds16(const unsigned short* g, unsigned short* l) {
  __builtin_amdgcn_global_load_lds((GV*)g, (LV*)l, 16, 0, 0);
}

template<int N> __device__ __forceinline__ void vmcnt_wait() {
  if constexpr (N == 8)      asm volatile("s_waitcnt vmcnt(8)" ::: "memory");
  else if constexpr (N == 6) asm volatile("s_waitcnt vmcnt(6)" ::: "memory");
  else if constexpr (N == 4) asm volatile("s_waitcnt vmcnt(4)" ::: "memory");
  else if constexpr (N == 2) asm volatile("s_waitcnt vmcnt(2)" ::: "memory");
  else                       asm volatile("s_waitcnt vmcnt(0)" ::: "memory");
}

// ---------------------------------------------------------------------------
// fp32 [K][N] -> bf16 [N][K] transpose+convert (32x32 tiles via LDS).
// ---------------------------------------------------------------------------
__global__ __launch_bounds__(256) void transpose_cvt(
    const float* __restrict__ in, unsigned short* __restrict__ outT, int K, int N)
{
  __shared__ float t[32][33];
  const int n0 = blockIdx.x * 32, k0 = blockIdx.y * 32;
  const int tx = threadIdx.x & 31, ty = threadIdx.x >> 5;   // ty 0..7
#pragma unroll
  for (int i = 0; i < 32; i += 8)
    t[ty + i][tx] = in[(size_t)(k0 + ty + i) * N + n0 + tx];
  __syncthreads();
#pragma unroll
  for (int i = 0; i < 32; i += 8)
    outT[(size_t)(n0 + ty + i) * K + k0 + tx] = f2bf(t[tx][ty + i]);
}

// ---------------------------------------------------------------------------
// fp32 -> bf16 elementwise (8 el/thread).
// ---------------------------------------------------------------------------
__global__ __launch_bounds__(256) void cvt_f32_bf16(
    const float* __restrict__ in, unsigned short* __restrict__ out)
{
  int i = (blockIdx.x * 256 + threadIdx.x) * 8;
  float4 a = *(const float4*)(in + i);
  float4 b = *(const float4*)(in + i + 4);
  U8 t;
  t.u[0] = f2bf(a.x); t.u[1] = f2bf(a.y); t.u[2] = f2bf(a.z); t.u[3] = f2bf(a.w);
  t.u[4] = f2bf(b.x); t.u[5] = f2bf(b.y); t.u[6] = f2bf(b.z); t.u[7] = f2bf(b.w);
  *(int4*)(out + i) = t.i4;
}

// ---------------------------------------------------------------------------
// m97-style GEMM (kept for WO): A [M][K] bf16, Bt [N][K] bf16, C [M][N].
// 128x128 tile, BK=32, 256 thr = 4 waves; wave does a 64x64 quadrant.
// ---------------------------------------------------------------------------
template<bool C_F32>
__global__ __launch_bounds__(256) void gemm_bt(
    const unsigned short* __restrict__ A,
    const unsigned short* __restrict__ Bt,
    void* __restrict__ C_, int M, int N, int K)
{
  __shared__ __align__(16) unsigned short As[128 * 32];
  __shared__ __align__(16) unsigned short Bs[128 * 32];

  const int tid  = threadIdx.x;
  const int wave = tid >> 6;
  const int lane = tid & 63;
  const int quad = lane >> 4;
  const int l16  = lane & 15;
  const int m0 = blockIdx.y * 128, n0 = blockIdx.x * 128;
  const int mw = (wave & 1) * 64, nw = (wave >> 1) * 64;

  floatx4 acc[4][4] = {};

  for (int k0 = 0; k0 < K; k0 += 32) {
#pragma unroll
    for (int p = 0; p < 2; p++) {
      int c = wave * 128 + p * 64 + lane;
      gload_lds16(A  + (size_t)(m0 + (c >> 2)) * K + k0 + (c & 3) * 8,
                  As + (wave * 128 + p * 64) * 8);
      gload_lds16(Bt + (size_t)(n0 + (c >> 2)) * K + k0 + (c & 3) * 8,
                  Bs + (wave * 128 + p * 64) * 8);
    }
    __syncthreads();

    bf16x8 af[4], bf[4];
#pragma unroll
    for (int mt = 0; mt < 4; mt++)
      af[mt] = *(const bf16x8*)(As + (mw + mt * 16 + l16) * 32 + quad * 8);
#pragma unroll
    for (int nt = 0; nt < 4; nt++)
      bf[nt] = *(const bf16x8*)(Bs + (nw + nt * 16 + l16) * 32 + quad * 8);
#pragma unroll
    for (int mt = 0; mt < 4; mt++)
#pragma unroll
      for (int nt = 0; nt < 4; nt++)
        acc[mt][nt] = mfma16(af[mt], bf[nt], acc[mt][nt]);
    __syncthreads();
  }

#pragma unroll
  for (int mt = 0; mt < 4; mt++)
#pragma unroll
    for (int nt = 0; nt < 4; nt++)
#pragma unroll
      for (int i = 0; i < 4; i++) {
        int r = m0 + mw + mt * 16 + quad * 4 + i;
        int c = n0 + nw + nt * 16 + l16;
        if (C_F32) ((float*)C_)[(size_t)r * N + c] = acc[mt][nt][i];
        else ((unsigned short*)C_)[(size_t)r * N + c] = f2bf(acc[mt][nt][i]);
      }
}

// ---------------------------------------------------------------------------
// 8-phase 256x256 pipelined GEMM (m201 schedule, re-derived).
// 8 waves = 2M x 4N; per-wave 128x64 C (8x4 fragments); BK=64, 2 K-steps.
// LDS: As/Bs[2][256*64] = 128 KiB, buf0 = even K-tiles, buf1 = odd.
// Iteration i (tiles 2i, 2i+1):
//   phases 0-3: compute buf0 quadrants (m0n0),(m0n1),(m1n1),(m1n0),
//               staging tile 2i+1 units [Am0,Bn0,Bn1,Am1] JIT into buf1;
//   phases 4-7: compute buf1 same order, staging tile 2i+2 into buf0.
// Each phase first-consumes exactly one unit, staged 4 phases earlier.
// vmcnt(4) gates at phase-ends {0,1,3,4,5,7}: retires exactly the 1-2 units
// the next phase needs, always leaves 2 units (4 loads) in flight (T4).
// Last iteration: p4-7 stage nothing; gates drain 4 -> 2 -> 0.
// Swizzle: 16B chunk j of row stored at j ^ (row&7) (inverse folded into the
// per-lane global source; gload_lds dest stays linear = wave base + lane*16).
// ---------------------------------------------------------------------------
template<bool C_F32>
__global__ __launch_bounds__(512, 2) void gemm8(
    const unsigned short* __restrict__ A,
    const unsigned short* __restrict__ Bt,
    void* __restrict__ C_, int M, int N, int K)
{
  __shared__ __align__(16) unsigned short As[2][256 * 64];
  __shared__ __align__(16) unsigned short Bs[2][256 * 64];

  // XCD swizzle: same-bx blocks (sharing a B-panel) land on one XCD.
  const int nwg  = gridDim.x * gridDim.y;
  const int bid0 = blockIdx.y * gridDim.x + blockIdx.x;
  const int wg   = (bid0 & 7) * (nwg >> 3) + (bid0 >> 3);
  const int bx = wg % gridDim.x, by = wg / gridDim.x;
  const int m0 = by * 256, n0 = bx * 256;

  const int tid  = threadIdx.x;
  const int wave = tid >> 6, lane = tid & 63;
  const int quad = lane >> 4, l16 = lane & 15;
  const int wm = wave >> 2, wn = wave & 3;

  floatx4 acc[8][4] = {};
  bf16x8 af[4][2];        // current A m-slice (reloaded per mq)
  bf16x8 bfr[2][2][2];    // both B n-slices held across the tile

  // A-unit (mq): 16 KB = rows {s*128+mq*64+[0,64)} s=0,1; 2 loads/thread.
#define STAGE_A8(buf_, mq_, kt_) do {                                           \
    _Pragma("unroll")                                                           \
    for (int s = 0; s < 2; s++) {                                               \
      int row = s * 128 + (mq_) * 64 + (tid >> 3);                              \
      gload_lds16(A + (size_t)(m0 + row) * K + (kt_) * 64                       \
                    + (((tid & 7) ^ (row & 7)) * 8),                            \
                  &As[buf_][(s * 128 + (mq_) * 64 + wave * 8) * 64]);           \
    } } while (0)

  // B-unit (nq): 16 KB = rows {r*64+nq*32+[0,32)} r=0..3; 2 loads/thread.
#define STAGE_B8(buf_, nq_, kt_) do {                                           \
    _Pragma("unroll")                                                           \
    for (int s = 0; s < 2; s++) {                                               \
      int c = s * 512 + tid;                                                    \
      int row = (c >> 8) * 64 + (nq_) * 32 + ((c >> 3) & 31);                   \
      gload_lds16(Bt + (size_t)(n0 + row) * K + (kt_) * 64                      \
                    + (((tid & 7) ^ (row & 7)) * 8),                            \
                  &Bs[buf_][((s * 2 + (wave >> 2)) * 64 + (nq_) * 32            \
                            + (wave & 3) * 8) * 64]);                           \
    } } while (0)

#define LOAD_AF8(buf_, mq_) do {                                                \
    _Pragma("unroll")                                                           \
    for (int m = 0; m < 4; m++)                                                 \
    _Pragma("unroll")                                                           \
      for (int ks = 0; ks < 2; ks++) {                                          \
        int row = wm * 128 + (mq_) * 64 + m * 16 + l16;                         \
        af[m][ks] = *(const bf16x8*)(&As[buf_][row * 64                         \
                       + (((ks * 4 + quad) ^ (l16 & 7)) * 8)]);                 \
      } } while (0)

#define LOAD_BF8(buf_, nq_) do {                                                \
    _Pragma("unroll")                                                           \
    for (int n = 0; n < 2; n++)                                                 \
    _Pragma("unroll")                                                           \
      for (int ks = 0; ks < 2; ks++) {                                          \
        int row = wn * 64 + (nq_) * 32 + n * 16 + l16;                          \
        bfr[nq_][n][ks] = *(const bf16x8*)(&Bs[buf_][row * 64                   \
                       + (((ks * 4 + quad) ^ (l16 & 7)) * 8)]);                 \
      } } while (0)

#define MFMA_Q8(mq_, nq_) do {                                                  \
    __builtin_amdgcn_s_setprio(1);                                              \
    _Pragma("unroll")                                                           \
    for (int ks = 0; ks < 2; ks++)                                              \
    _Pragma("unroll")                                                           \
      for (int m = 0; m < 4; m++)                                               \
      _Pragma("unroll")                                                         \
        for (int n = 0; n < 2; n++)                                             \
          acc[(mq_) * 4 + m][(nq_) * 2 + n] = mfma16(af[m][ks],                 \
              bfr[nq_][n][ks], acc[(mq_) * 4 + m][(nq_) * 2 + n]);              \
    __builtin_amdgcn_s_setprio(0);                                              \
  } while (0)

#define BAR_MID() do { __builtin_amdgcn_s_barrier();                            \
    asm volatile("s_waitcnt lgkmcnt(0)" ::: "memory");                          \
    __builtin_amdgcn_sched_barrier(0); } while (0)

#define GATE(n_) do { vmcnt_wait<n_>();                                         \
    __builtin_amdgcn_sched_barrier(0);                                          \
    __builtin_amdgcn_s_barrier(); } while (0)

#define ENDP() __builtin_amdgcn_s_barrier()

  const int NIT = K >> 7;                 // 2 K-tiles (of 64) per iteration

  // prologue = virtual phases 4-7: tile 0 -> buf0, order [Am0,Bn0,Bn1,Am1]
  STAGE_A8(0, 0, 0); STAGE_B8(0, 0, 0); STAGE_B8(0, 1, 0); STAGE_A8(0, 1, 0);
  vmcnt_wait<4>();                        // Am0,Bn0 landed; Bn1,Am1 in flight
  __builtin_amdgcn_s_barrier();

  for (int i = 0; i < NIT; i++) {
    const int t1 = 2 * i + 1, t2 = 2 * i + 2;
    const bool more = (i + 1 < NIT);
    // ---- phase 0: buf0 q(m0,n0); stage buf1.Am0 ----
    LOAD_AF8(0, 0); LOAD_BF8(0, 0);
    STAGE_A8(1, 0, t1);
    BAR_MID(); MFMA_Q8(0, 0); GATE(4);    // retires prev Bn1
    // ---- phase 1: buf0 q(m0,n1); stage buf1.Bn0 ----
    LOAD_BF8(0, 1);
    STAGE_B8(1, 0, t1);
    BAR_MID(); MFMA_Q8(0, 1); GATE(4);    // retires prev Am1
    // ---- phase 2: buf0 q(m1,n1); stage buf1.Bn1 ----
    LOAD_AF8(0, 1);
    STAGE_B8(1, 1, t1);
    BAR_MID(); MFMA_Q8(1, 1); ENDP();     // phase 3 consumes nothing new
    // ---- phase 3: buf0 q(m1,n0) (all operands in regs); stage buf1.Am1 ----
    STAGE_A8(1, 1, t1);
    BAR_MID(); MFMA_Q8(1, 0); GATE(4);    // retires buf1 Am0,Bn0
    // ---- phase 4: buf1 q(m0,n0); stage buf0.Am0(next) ----
    LOAD_AF8(1, 0); LOAD_BF8(1, 0);
    if (more) STAGE_A8(0, 0, t2);
    BAR_MID(); MFMA_Q8(0, 0);
    if (more) GATE(4); else GATE(2);      // retires buf1 Bn1
    // ---- phase 5: buf1 q(m0,n1); stage buf0.Bn0(next) ----
    LOAD_BF8(1, 1);
    if (more) STAGE_B8(0, 0, t2);
    BAR_MID(); MFMA_Q8(0, 1);
    if (more) GATE(4); else GATE(0);      // retires buf1 Am1
    // ---- phase 6: buf1 q(m1,n1); stage buf0.Bn1(next) ----
    LOAD_AF8(1, 1);
    if (more) STAGE_B8(0, 1, t2);
    BAR_MID(); MFMA_Q8(1, 1); ENDP();     // phase 7 consumes nothing new
    // ---- phase 7: buf1 q(m1,n0); stage buf0.Am1(next) ----
    if (more) STAGE_A8(0, 1, t2);
    BAR_MID(); MFMA_Q8(1, 0);
    if (more) GATE(4); else ENDP();       // retires next Am0,Bn0
  }

#undef STAGE_A8
#undef STAGE_B8
#undef LOAD_AF8
#undef LOAD_BF8
#undef MFMA_Q8
#undef BAR_MID
#undef GATE
#undef ENDP

#pragma unroll
  for (int mq = 0; mq < 2; mq++)
#pragma unroll
    for (int m = 0; m < 4; m++)
#pragma unroll
      for (int nq = 0; nq < 2; nq++)
#pragma unroll
        for (int n = 0; n < 2; n++)
#pragma unroll
          for (int i2 = 0; i2 < 4; i2++) {
            int r = m0 + wm * 128 + mq * 64 + m * 16 + quad * 4 + i2;
            int c = n0 + wn * 64 + nq * 32 + n * 16 + l16;
            float v = acc[mq * 4 + m][nq * 2 + n][i2];
            if (C_F32) ((float*)C_)[(size_t)r * N + c] = v;
            else ((unsigned short*)C_)[(size_t)r * N + c] = f2bf(v);
          }
}

// ---------------------------------------------------------------------------
// RoPE in-place on fused qkv [S][6144]: q cols scaled by 1/sqrt(HD) (folds the
// attention scale), k cols unscaled. cos/sin fp32 [s][p].
// ---------------------------------------------------------------------------
__global__ __launch_bounds__(256) void rope_kernel(
    unsigned short* __restrict__ qkv,
    const float* __restrict__ fcos, const float* __restrict__ fsin)
{
  int idx = blockIdx.x * 256 + threadIdx.x;   // S_LEN*(NH+NKV)*64 threads
  int p = idx & 63;
  int t = idx >> 6;
  int h = t % (NH + NKV);
  int s = t / (NH + NKV);

  float c  = fcos[s * 64 + p];
  float sn = fsin[s * 64 + p];
  const float qs = 0.08838834764831845f;      // 1/sqrt(128)

  unsigned short* base;
  float m;
  if (h < NH) { base = qkv + (size_t)s * QKV_LD + h * HD + p * 2; m = qs; }
  else { base = qkv + (size_t)s * QKV_LD + KOFF + (h - NH) * HD + p * 2; m = 1.f; }

  unsigned int both = *(const unsigned int*)base;
  float t0 = bf2f((unsigned short)(both & 0xffff));
  float t1 = bf2f((unsigned short)(both >> 16));
  unsigned int o0 = f2bf((t0 * c - t1 * sn) * m);
  unsigned int o1 = f2bf((t0 * sn + t1 * c) * m);
  *(unsigned int*)base = o0 | (o1 << 16);
}

// ---------------------------------------------------------------------------
// V transpose: vt[kv*HD + d][s] = qkv[s][VOFF + kv*HD + d]. (bf16)
// 32x32 LDS-tiled so both sides are coalesced.
// ---------------------------------------------------------------------------
__global__ __launch_bounds__(256) void vtrans_kernel(
    const unsigned short* __restrict__ qkv, unsigned short* __restrict__ vt)
{
  __shared__ unsigned short t[32][34];
  const int s0 = blockIdx.x * 32;                  // S_LEN/32 blocks
  const int d0 = blockIdx.y * 32;                  // (NKV*HD)/32 blocks
  const int tx = threadIdx.x & 31, ty = threadIdx.x >> 5;   // ty 0..7
#pragma unroll
  for (int i = 0; i < 32; i += 8)
    t[ty + i][tx] = qkv[(size_t)(s0 + ty + i) * QKV_LD + VOFF + d0 + tx];
  __syncthreads();
#pragma unroll
  for (int i = 0; i < 32; i += 8)
    vt[(size_t)(d0 + ty + i) * S_LEN + s0 + tx] = t[tx][ty + i];
}

// ---------------------------------------------------------------------------
// Flash attention, no-max softmax. Swapped QK^T (mfma(K,Q)) -> P lane-local,
// softmax in-register, PV A-frag via cross-quad shfl. Double-buffered K/V,
// one barrier per KV-iteration. Grid (NH, S/128); 4 waves; 2 blocks/CU.
// (verified round 3: 567 us total, attn no longer in top-5)
// ---------------------------------------------------------------------------
__global__ __launch_bounds__(256, 2) void attn_kernel(
    const unsigned short* __restrict__ qkv,
    const unsigned short* __restrict__ vt,
    unsigned short* __restrict__ o)
{
  __shared__ __align__(16) unsigned short Ks[2][64 * 136];
  __shared__ __align__(16) unsigned short Vs[2][128 * 72];

  const int h    = blockIdx.x;
  const int qblk = blockIdx.y;
  const int kvh  = h >> 2;
  const int tid  = threadIdx.x;
  const int lane = tid & 63;
  const int quad = lane >> 4;
  const int l16  = lane & 15;
  const int wave = tid >> 6;
  const int qr   = qblk * 128 + wave * 16;        // + mt*64

  bf16x8 qf[2][4];
#pragma unroll
  for (int mt = 0; mt < 2; mt++)
#pragma unroll
    for (int ks = 0; ks < 4; ks++)
      qf[mt][ks] = *(const bf16x8*)(qkv + (size_t)(qr + mt * 64 + l16) * QKV_LD
                                    + h * HD + ks * 32 + quad * 8);

  floatx4 accO[2][8] = {};
  float l_i[2] = {0.f, 0.f};

  int4 pk[4], pv4[4];
#define LOAD_TILE(kb_) do {                                                     \
    _Pragma("unroll")                                                           \
    for (int j = 0; j < 4; j++) {                                               \
      int c = tid + 256 * j;                                                    \
      pk[j] = *(const int4*)(qkv + (size_t)((kb_) * 64 + (c >> 4)) * QKV_LD     \
                              + KOFF + kvh * HD + (c & 15) * 8);                \
      pv4[j] = *(const int4*)(vt + (size_t)(kvh * HD + (c >> 3)) * S_LEN        \
                              + (kb_) * 64 + (c & 7) * 8);                      \
    } } while (0)
#define STORE_TILE(b_) do {                                                     \
    _Pragma("unroll")                                                           \
    for (int j = 0; j < 4; j++) {                                               \
      int c = tid + 256 * j;                                                    \
      *(int4*)(Ks[b_] + (c >> 4) * 136 + (c & 15) * 8) = pk[j];                 \
      *(int4*)(Vs[b_] + (c >> 3) * 72 + (c & 7) * 8) = pv4[j];                  \
    } } while (0)

  LOAD_TILE(0);
  STORE_TILE(0);
  __syncthreads();

  const int srcA = ((quad & 1) << 5) | l16;       // quad-pair source lane
  const bool hi  = (quad & 2);                    // nt = 2*k2 + (quad>>1)

  for (int kb = 0; kb < S_LEN / 64; kb++) {
    const int cur = kb & 1;
    if (kb + 1 < S_LEN / 64) LOAD_TILE(kb + 1);   // global->reg, spans compute

    const unsigned short* Ksc = Ks[cur];
    const unsigned short* Vsc = Vs[cur];

    // ---- S^T = K Q^T : lane holds P-row slice for q=l16 ----
    floatx4 sacc[2][4] = {};
    __builtin_amdgcn_s_setprio(1);
#pragma unroll
    for (int ks = 0; ks < 4; ks++)
#pragma unroll
      for (int nt = 0; nt < 4; nt++) {
        bf16x8 kf = *(const bf16x8*)(Ksc + (nt * 16 + l16) * 136 + ks * 32 + quad * 8);
        sacc[0][nt] = mfma16(kf, qf[0][ks], sacc[0][nt]);
        sacc[1][nt] = mfma16(kf, qf[1][ks], sacc[1][nt]);
      }
    __builtin_amdgcn_s_setprio(0);

    // ---- P = exp(S); per-lane l partial; pack to bf16 words in-register ----
    unsigned int wp[2][2][4];   // [mt][word 0/1][nt]
#pragma unroll
    for (int mt = 0; mt < 2; mt++) {
      float ls = 0.f;
#pragma unroll
      for (int nt = 0; nt < 4; nt++) {
        float e0 = __expf(sacc[mt][nt][0]);
        float e1 = __expf(sacc[mt][nt][1]);
        float e2 = __expf(sacc[mt][nt][2]);
        float e3 = __expf(sacc[mt][nt][3]);
        ls += (e0 + e1) + (e2 + e3);
        wp[mt][0][nt] = (unsigned int)f2bf(e0) | ((unsigned int)f2bf(e1) << 16);
        wp[mt][1][nt] = (unsigned int)f2bf(e2) | ((unsigned int)f2bf(e3) << 16);
      }
      l_i[mt] += ls;
    }

    // ---- O += P V ; A-fragment via cross-quad exchange ----
#pragma unroll
    for (int k2 = 0; k2 < 2; k2++) {
      bf16x8 paf[2];
#pragma unroll
      for (int mt = 0; mt < 2; mt++) {
        const int ntl = k2 * 2, nth = k2 * 2 + 1;
        unsigned int a0 = __shfl((int)wp[mt][0][ntl], srcA, 64);
        unsigned int b0 = __shfl((int)wp[mt][0][nth], srcA, 64);
        unsigned int a1 = __shfl((int)wp[mt][1][ntl], srcA, 64);
        unsigned int b1 = __shfl((int)wp[mt][1][nth], srcA, 64);
        unsigned int a2 = __shfl((int)wp[mt][0][ntl], srcA + 16, 64);
        unsigned int b2 = __shfl((int)wp[mt][0][nth], srcA + 16, 64);
        unsigned int a3 = __shfl((int)wp[mt][1][ntl], srcA + 16, 64);
        unsigned int b3 = __shfl((int)wp[mt][1][nth], srcA + 16, 64);
        U32x4 pw;
        pw.u[0] = hi ? b0 : a0;
        pw.u[1] = hi ? b1 : a1;
        pw.u[2] = hi ? b2 : a2;
        pw.u[3] = hi ? b3 : a3;
        paf[mt] = pw.v;
      }
      __builtin_amdgcn_s_setprio(1);
#pragma unroll
      for (int dt = 0; dt < 8; dt++) {
        bf16x8 vf = *(const bf16x8*)(Vsc + (dt * 16 + l16) * 72 + k2 * 32 + quad * 8);
        accO[0][dt] = mfma16(paf[0], vf, accO[0][dt]);
        accO[1][dt] = mfma16(paf[1], vf, accO[1][dt]);
      }
      __builtin_amdgcn_s_setprio(0);
    }

    if (kb + 1 < S_LEN / 64) STORE_TILE(cur ^ 1);   // buf was drained last iter
    __syncthreads();
  }

  // ---- l: sum the 4 quad partials for each q=l16; broadcast to output rows --
#pragma unroll
  for (int mt = 0; mt < 2; mt++) {
    l_i[mt] += __shfl_xor(l_i[mt], 16, 64);
    l_i[mt] += __shfl_xor(l_i[mt], 32, 64);
  }

#pragma unroll
  for (int mt = 0; mt < 2; mt++) {
    float lq[4];
#pragma unroll
    for (int i = 0; i < 4; i++) lq[i] = __shfl(l_i[mt], quad * 4 + i, 64);
#pragma unroll
    for (int dt = 0; dt < 8; dt++)
#pragma unroll
      for (int i = 0; i < 4; i++) {
        float val = accO[mt][dt][i] / lq[i];
        o[(size_t)(qr + mt * 64 + quad * 4 + i) * (NH * HD) + h * HD + dt * 16 + l16]
            = f2bf(val);
      }
  }
#undef LOAD_TILE
#undef STORE_TILE
}

// ---------------------------------------------------------------------------
extern "C" void kernel_launch(void* const* d_in, const int* in_sizes, int n_in,
                              void* d_out, int out_size, void* d_ws, size_t ws_size,
                              hipStream_t stream)
{
  const float* x    = (const float*)d_in[0];
  const float* fcos = (const float*)d_in[1];
  const float* fsin = (const float*)d_in[2];
  const float* wq   = (const float*)d_in[3];
  const float* wk   = (const float*)d_in[4];
  const float* wv   = (const float*)d_in[5];
  const float* wo   = (const float*)d_in[6];
  float* out = (float*)d_out;

  unsigned short* ws = (unsigned short*)d_ws;
  unsigned short* xb   = ws;                                   // S*DIM
  unsigned short* wT   = xb   + (size_t)S_LEN * DIM;           // [6144][4096]
  unsigned short* woT  = wT   + (size_t)QKV_LD * DIM;          // [4096][4096]
  unsigned short* qkv  = woT  + (size_t)DIM * (NH * HD);       // [S][6144]
  unsigned short* vt   = qkv  + (size_t)S_LEN * QKV_LD;        // [NKV][HD][S]
  unsigned short* attn = vt   + (size_t)S_LEN * (NKV * HD);    // [S][4096]
  // total ~146 MB of d_ws

  // one-time per launch: x -> bf16; weights -> bf16 [N][K], q|k|v contiguous
  cvt_f32_bf16<<<(S_LEN * DIM) / (256 * 8), 256, 0, stream>>>(x, xb);
  transpose_cvt<<<dim3(DIM / 32, DIM / 32),        256, 0, stream>>>(wq, wT, DIM, DIM);
  transpose_cvt<<<dim3((NKV * HD) / 32, DIM / 32), 256, 0, stream>>>(wk, wT + (size_t)KOFF * DIM, DIM, NKV * HD);
  transpose_cvt<<<dim3((NKV * HD) / 32, DIM / 32), 256, 0, stream>>>(wv, wT + (size_t)VOFF * DIM, DIM, NKV * HD);
  transpose_cvt<<<dim3(DIM / 32, (NH * HD) / 32),  256, 0, stream>>>(wo, woT, NH * HD, DIM);

  // fused QKV projection: [S][6144], 8-phase 256x256 -> 192 blocks (1 round)
  gemm8<false>
      <<<dim3(QKV_LD / 256, S_LEN / 256), 512, 0, stream>>>(xb, wT, qkv, S_LEN, QKV_LD, DIM);

  rope_kernel<<<(S_LEN * (NH + NKV) * 64) / 256, 256, 0, stream>>>(qkv, fcos, fsin);
  vtrans_kernel<<<dim3(S_LEN / 32, (NKV * HD) / 32), 256, 0, stream>>>(qkv, vt);

  attn_kernel<<<dim3(NH, S_LEN / 128), 256, 0, stream>>>(qkv, vt, attn);

  // output projection -> fp32 d_out (m97 structure, known-good)
  gemm_bt<true><<<dim3(DIM / 128, S_LEN / 128), 256, 0, stream>>>(attn, woT, out, S_LEN, DIM, NH * HD);
}

// Round 7
// 554.401 us; speedup vs baseline: 1.1094x; 1.0233x over previous
//
#include <hip/hip_runtime.h>

#define S_LEN 2048
#define DIM   4096
#define NH    32
#define NKV   8
#define HD    128
#define QKV_LD 6144          // fused qkv row: [q 4096 | k 1024 | v 1024]
#define KOFF 4096
#define VOFF 5120

typedef __attribute__((ext_vector_type(8))) __bf16 bf16x8;
typedef __attribute__((ext_vector_type(4))) float  floatx4;

union U8 { unsigned short u[8]; bf16x8 v; int4 i4; };
union U32x4 { unsigned int u[4]; bf16x8 v; };

__device__ inline unsigned short f2bf(float f) {
  unsigned int u = __float_as_uint(f);
  u += 0x7fff + ((u >> 16) & 1);          // round-to-nearest-even
  return (unsigned short)(u >> 16);
}
__device__ inline float bf2f(unsigned short h) {
  return __uint_as_float(((unsigned int)h) << 16);
}

__device__ inline floatx4 mfma16(bf16x8 a, bf16x8 b, floatx4 c) {
  return __builtin_amdgcn_mfma_f32_16x16x32_bf16(a, b, c, 0, 0, 0);
}

// async global->LDS, 16B per lane. lds dest = wave-uniform base + lane*16;
// global src address is PER-LANE (enables pre-swizzled sources, m173).
typedef __attribute__((address_space(1))) void GV;
typedef __attribute__((address_space(3))) void LV;
__device__ inline void gload_lds16(const unsigned short* g, unsigned short* l) {
  __builtin_amdgcn_global_load_lds((GV*)g, (LV*)l, 16, 0, 0);
}

template<int N> __device__ __forceinline__ void vmcnt_wait() {
  if constexpr (N == 12)      asm volatile("s_waitcnt vmcnt(12)" ::: "memory");
  else if constexpr (N == 10) asm volatile("s_waitcnt vmcnt(10)" ::: "memory");
  else if constexpr (N == 8)  asm volatile("s_waitcnt vmcnt(8)" ::: "memory");
  else if constexpr (N == 4)  asm volatile("s_waitcnt vmcnt(4)" ::: "memory");
  else if constexpr (N == 2)  asm volatile("s_waitcnt vmcnt(2)" ::: "memory");
  else                        asm volatile("s_waitcnt vmcnt(0)" ::: "memory");
}

// ---------------------------------------------------------------------------
// fp32 [K][N] -> bf16 [N][K] transpose+convert (32x32 tiles via LDS).
// ---------------------------------------------------------------------------
__global__ __launch_bounds__(256) void transpose_cvt(
    const float* __restrict__ in, unsigned short* __restrict__ outT, int K, int N)
{
  __shared__ float t[32][33];
  const int n0 = blockIdx.x * 32, k0 = blockIdx.y * 32;
  const int tx = threadIdx.x & 31, ty = threadIdx.x >> 5;   // ty 0..7
#pragma unroll
  for (int i = 0; i < 32; i += 8)
    t[ty + i][tx] = in[(size_t)(k0 + ty + i) * N + n0 + tx];
  __syncthreads();
#pragma unroll
  for (int i = 0; i < 32; i += 8)
    outT[(size_t)(n0 + ty + i) * K + k0 + tx] = f2bf(t[tx][ty + i]);
}

// ---------------------------------------------------------------------------
// fp32 -> bf16 elementwise (8 el/thread).
// ---------------------------------------------------------------------------
__global__ __launch_bounds__(256) void cvt_f32_bf16(
    const float* __restrict__ in, unsigned short* __restrict__ out)
{
  int i = (blockIdx.x * 256 + threadIdx.x) * 8;
  float4 a = *(const float4*)(in + i);
  float4 b = *(const float4*)(in + i + 4);
  U8 t;
  t.u[0] = f2bf(a.x); t.u[1] = f2bf(a.y); t.u[2] = f2bf(a.z); t.u[3] = f2bf(a.w);
  t.u[4] = f2bf(b.x); t.u[5] = f2bf(b.y); t.u[6] = f2bf(b.z); t.u[7] = f2bf(b.w);
  *(int4*)(out + i) = t.i4;
}

// ---------------------------------------------------------------------------
// m97-style GEMM (kept for WO): A [M][K] bf16, Bt [N][K] bf16, C [M][N].
// 128x128 tile, BK=32, 256 thr = 4 waves; wave does a 64x64 quadrant.
// ---------------------------------------------------------------------------
template<bool C_F32>
__global__ __launch_bounds__(256) void gemm_bt(
    const unsigned short* __restrict__ A,
    const unsigned short* __restrict__ Bt,
    void* __restrict__ C_, int M, int N, int K)
{
  __shared__ __align__(16) unsigned short As[128 * 32];
  __shared__ __align__(16) unsigned short Bs[128 * 32];

  const int tid  = threadIdx.x;
  const int wave = tid >> 6;
  const int lane = tid & 63;
  const int quad = lane >> 4;
  const int l16  = lane & 15;
  const int m0 = blockIdx.y * 128, n0 = blockIdx.x * 128;
  const int mw = (wave & 1) * 64, nw = (wave >> 1) * 64;

  floatx4 acc[4][4] = {};

  for (int k0 = 0; k0 < K; k0 += 32) {
#pragma unroll
    for (int p = 0; p < 2; p++) {
      int c = wave * 128 + p * 64 + lane;
      gload_lds16(A  + (size_t)(m0 + (c >> 2)) * K + k0 + (c & 3) * 8,
                  As + (wave * 128 + p * 64) * 8);
      gload_lds16(Bt + (size_t)(n0 + (c >> 2)) * K + k0 + (c & 3) * 8,
                  Bs + (wave * 128 + p * 64) * 8);
    }
    __syncthreads();

    bf16x8 af[4], bf[4];
#pragma unroll
    for (int mt = 0; mt < 4; mt++)
      af[mt] = *(const bf16x8*)(As + (mw + mt * 16 + l16) * 32 + quad * 8);
#pragma unroll
    for (int nt = 0; nt < 4; nt++)
      bf[nt] = *(const bf16x8*)(Bs + (nw + nt * 16 + l16) * 32 + quad * 8);
#pragma unroll
    for (int mt = 0; mt < 4; mt++)
#pragma unroll
      for (int nt = 0; nt < 4; nt++)
        acc[mt][nt] = mfma16(af[mt], bf[nt], acc[mt][nt]);
    __syncthreads();
  }

#pragma unroll
  for (int mt = 0; mt < 4; mt++)
#pragma unroll
    for (int nt = 0; nt < 4; nt++)
#pragma unroll
      for (int i = 0; i < 4; i++) {
        int r = m0 + mw + mt * 16 + quad * 4 + i;
        int c = n0 + nw + nt * 16 + l16;
        if (C_F32) ((float*)C_)[(size_t)r * N + c] = acc[mt][nt][i];
        else ((unsigned short*)C_)[(size_t)r * N + c] = f2bf(acc[mt][nt][i]);
      }
}

// ---------------------------------------------------------------------------
// 8-phase 256x256 pipelined GEMM, v2: ASAP staging + deep vmcnt ledger.
// 8 waves = 2M x 4N; per-wave 128x64 C; BK=64; buf0 = even K-tiles, buf1 = odd.
// Iteration i: ph0-3 compute buf0 (tile 2i) quadrants (m0n0),(m0n1),(m1n1),
// (m1n0); ph4-7 compute buf1 (tile 2i+1). Units (16 KB): Am0,Bn0,Bn1,Am1.
// STAGING (v2): each unit re-staged IMMEDIATELY after its last reader phase:
//   ph1: E'Am0,E'Bn0 (tile 2i+2->buf0)   [freed by ph0 reads]
//   ph2: E'Bn1  ph3: E'Am1
//   ph5: O'Am0,O'Bn0 (tile 2i+3->buf1)   ph6: O'Bn1  ph7: O'Am1
// -> consumption lead = 5-7 phases (~3-5us >> 900cy HBM miss).
// GATES (2 loads/unit/wave; ledger verified steady-state):
//   end-ph0 vm(10) retires eBn1; ph1 vm(12) eAm1; ph3 vm(12) oAm0,oBn0;
//   ph4 vm(10) oBn1; ph5 vm(12) oAm1; ph7 vm(12) E'Am0,E'Bn0.
//   Final iter (no stages): ph1 vm(8), ph3 vm(4), ph4 vm(2), ph5 vm(0).
// WAR safety: a unit is staged only after a {lgkmcnt(0)->barrier} that all
// its readers passed. vmcnt is per-wave; the barrier after each gate makes
// the whole unit (all 8 waves' portions) resident before any read.
// XCD map (grid 24x8 ONLY): xcd=bid&7 owns a 4(by)x6(bx) rect -> per-XCD
// L2 stream/K-slab = 160 KB (vs full-B 768 KB with the old by-grouping).
// Swizzle: 16B chunk j of row at j^(row&7), inverse folded into global src.
// ---------------------------------------------------------------------------
template<bool C_F32>
__global__ __launch_bounds__(512, 2) void gemm8(
    const unsigned short* __restrict__ A,
    const unsigned short* __restrict__ Bt,
    void* __restrict__ C_, int M, int N, int K)
{
  __shared__ __align__(16) unsigned short As[2][256 * 64];
  __shared__ __align__(16) unsigned short Bs[2][256 * 64];

  // rect XCD map — REQUIRES grid == (24, 8).
  const int bid0 = blockIdx.y * gridDim.x + blockIdx.x;
  const int xcd = bid0 & 7, j = bid0 >> 3;
  const int by = (xcd >> 2) * 4 + j / 6;
  const int bx = (xcd & 3) * 6 + j % 6;
  const int m0 = by * 256, n0 = bx * 256;

  const int tid  = threadIdx.x;
  const int wave = tid >> 6, lane = tid & 63;
  const int quad = lane >> 4, l16 = lane & 15;
  const int wm = wave >> 2, wn = wave & 3;

  floatx4 acc[8][4] = {};
  bf16x8 af[4][2];        // current A m-slice (reloaded per mq)
  bf16x8 bfr[2][2][2];    // both B n-slices held across the tile

  // A-unit (mq): 16 KB = rows {s*128+mq*64+[0,64)} s=0,1; 2 loads/thread.
#define STAGE_A8(buf_, mq_, kt_) do {                                           \
    _Pragma("unroll")                                                           \
    for (int s = 0; s < 2; s++) {                                               \
      int row = s * 128 + (mq_) * 64 + (tid >> 3);                              \
      gload_lds16(A + (size_t)(m0 + row) * K + (kt_) * 64                       \
                    + (((tid & 7) ^ (row & 7)) * 8),                            \
                  &As[buf_][(s * 128 + (mq_) * 64 + wave * 8) * 64]);           \
    } } while (0)

  // B-unit (nq): 16 KB = rows {r*64+nq*32+[0,32)} r=0..3; 2 loads/thread.
#define STAGE_B8(buf_, nq_, kt_) do {                                           \
    _Pragma("unroll")                                                           \
    for (int s = 0; s < 2; s++) {                                               \
      int c = s * 512 + tid;                                                    \
      int row = (c >> 8) * 64 + (nq_) * 32 + ((c >> 3) & 31);                   \
      gload_lds16(Bt + (size_t)(n0 + row) * K + (kt_) * 64                      \
                    + (((tid & 7) ^ (row & 7)) * 8),                            \
                  &Bs[buf_][((s * 2 + (wave >> 2)) * 64 + (nq_) * 32            \
                            + (wave & 3) * 8) * 64]);                           \
    } } while (0)

#define LOAD_AF8(buf_, mq_) do {                                                \
    _Pragma("unroll")                                                           \
    for (int m = 0; m < 4; m++)                                                 \
    _Pragma("unroll")                                                           \
      for (int ks = 0; ks < 2; ks++) {                                          \
        int row = wm * 128 + (mq_) * 64 + m * 16 + l16;                         \
        af[m][ks] = *(const bf16x8*)(&As[buf_][row * 64                         \
                       + (((ks * 4 + quad) ^ (l16 & 7)) * 8)]);                 \
      } } while (0)

#define LOAD_BF8(buf_, nq_) do {                                                \
    _Pragma("unroll")                                                           \
    for (int n = 0; n < 2; n++)                                                 \
    _Pragma("unroll")                                                           \
      for (int ks = 0; ks < 2; ks++) {                                          \
        int row = wn * 64 + (nq_) * 32 + n * 16 + l16;                          \
        bfr[nq_][n][ks] = *(const bf16x8*)(&Bs[buf_][row * 64                   \
                       + (((ks * 4 + quad) ^ (l16 & 7)) * 8)]);                 \
      } } while (0)

#define MFMA_Q8(mq_, nq_) do {                                                  \
    __builtin_amdgcn_s_setprio(1);                                              \
    _Pragma("unroll")                                                           \
    for (int ks = 0; ks < 2; ks++)                                              \
    _Pragma("unroll")                                                           \
      for (int m = 0; m < 4; m++)                                               \
      _Pragma("unroll")                                                         \
        for (int n = 0; n < 2; n++)                                             \
          acc[(mq_) * 4 + m][(nq_) * 2 + n] = mfma16(af[m][ks],                 \
              bfr[nq_][n][ks], acc[(mq_) * 4 + m][(nq_) * 2 + n]);              \
    __builtin_amdgcn_s_setprio(0);                                              \
  } while (0)

#define BAR_MID() do { __builtin_amdgcn_s_barrier();                            \
    asm volatile("s_waitcnt lgkmcnt(0)" ::: "memory");                          \
    __builtin_amdgcn_sched_barrier(0); } while (0)

#define GATE(n_) do { vmcnt_wait<n_>();                                         \
    __builtin_amdgcn_sched_barrier(0);                                          \
    __builtin_amdgcn_s_barrier(); } while (0)

#define ENDP() __builtin_amdgcn_s_barrier()

  const int NIT = K >> 7;                 // 2 K-tiles (of 64) per iteration

  // prologue: tile0 -> buf0 (e1..e4), tile1 -> buf1 (o1..o4); 16 loads.
  STAGE_A8(0, 0, 0); STAGE_B8(0, 0, 0); STAGE_B8(0, 1, 0); STAGE_A8(0, 1, 0);
  STAGE_A8(1, 0, 1); STAGE_B8(1, 0, 1); STAGE_B8(1, 1, 1); STAGE_A8(1, 1, 1);
  vmcnt_wait<12>();                       // e1,e2 (Am0,Bn0) landed
  __builtin_amdgcn_s_barrier();

  for (int i = 0; i < NIT; i++) {
    const int tE = 2 * i + 2, tO = 2 * i + 3;
    const bool more = (i + 1 < NIT);
    // ---- phase 0: buf0 q(m0,n0) ----
    LOAD_AF8(0, 0); LOAD_BF8(0, 0);
    BAR_MID(); MFMA_Q8(0, 0); GATE(10);         // retire eBn1
    // ---- phase 1: buf0 q(m0,n1); stage E'Am0,E'Bn0 (buf0 freed by ph0) ----
    LOAD_BF8(0, 1);
    if (more) { STAGE_A8(0, 0, tE); STAGE_B8(0, 0, tE); }
    BAR_MID(); MFMA_Q8(0, 1);
    if (more) GATE(12); else GATE(8);           // retire eAm1
    // ---- phase 2: buf0 q(m1,n1); stage E'Bn1 ----
    LOAD_AF8(0, 1);
    if (more) STAGE_B8(0, 1, tE);
    BAR_MID(); MFMA_Q8(1, 1); ENDP();           // ph3 reads regs only
    // ---- phase 3: buf0 q(m1,n0); stage E'Am1 ----
    if (more) STAGE_A8(0, 1, tE);
    BAR_MID(); MFMA_Q8(1, 0);
    if (more) GATE(12); else GATE(4);           // retire oAm0,oBn0
    // ---- phase 4: buf1 q(m0,n0) ----
    LOAD_AF8(1, 0); LOAD_BF8(1, 0);
    BAR_MID(); MFMA_Q8(0, 0);
    if (more) GATE(10); else GATE(2);           // retire oBn1
    // ---- phase 5: buf1 q(m0,n1); stage O'Am0,O'Bn0 ----
    LOAD_BF8(1, 1);
    if (more) { STAGE_A8(1, 0, tO); STAGE_B8(1, 0, tO); }
    BAR_MID(); MFMA_Q8(0, 1);
    if (more) GATE(12); else GATE(0);           // retire oAm1
    // ---- phase 6: buf1 q(m1,n1); stage O'Bn1 ----
    LOAD_AF8(1, 1);
    if (more) STAGE_B8(1, 1, tO);
    BAR_MID(); MFMA_Q8(1, 1); ENDP();           // ph7 reads regs only
    // ---- phase 7: buf1 q(m1,n0); stage O'Am1 ----
    if (more) STAGE_A8(1, 1, tO);
    BAR_MID(); MFMA_Q8(1, 0);
    if (more) GATE(12); else ENDP();            // retire E'Am0,E'Bn0
  }

#undef STAGE_A8
#undef STAGE_B8
#undef LOAD_AF8
#undef LOAD_BF8
#undef MFMA_Q8
#undef BAR_MID
#undef GATE
#undef ENDP

#pragma unroll
  for (int mq = 0; mq < 2; mq++)
#pragma unroll
    for (int m = 0; m < 4; m++)
#pragma unroll
      for (int nq = 0; nq < 2; nq++)
#pragma unroll
        for (int n = 0; n < 2; n++)
#pragma unroll
          for (int i2 = 0; i2 < 4; i2++) {
            int r = m0 + wm * 128 + mq * 64 + m * 16 + quad * 4 + i2;
            int c = n0 + wn * 64 + nq * 32 + n * 16 + l16;
            float v = acc[mq * 4 + m][nq * 2 + n][i2];
            if (C_F32) ((float*)C_)[(size_t)r * N + c] = v;
            else ((unsigned short*)C_)[(size_t)r * N + c] = f2bf(v);
          }
}

// ---------------------------------------------------------------------------
// RoPE in-place on fused qkv [S][6144]: q cols scaled by 1/sqrt(HD) (folds the
// attention scale), k cols unscaled. cos/sin fp32 [s][p].
// ---------------------------------------------------------------------------
__global__ __launch_bounds__(256) void rope_kernel(
    unsigned short* __restrict__ qkv,
    const float* __restrict__ fcos, const float* __restrict__ fsin)
{
  int idx = blockIdx.x * 256 + threadIdx.x;   // S_LEN*(NH+NKV)*64 threads
  int p = idx & 63;
  int t = idx >> 6;
  int h = t % (NH + NKV);
  int s = t / (NH + NKV);

  float c  = fcos[s * 64 + p];
  float sn = fsin[s * 64 + p];
  const float qs = 0.08838834764831845f;      // 1/sqrt(128)

  unsigned short* base;
  float m;
  if (h < NH) { base = qkv + (size_t)s * QKV_LD + h * HD + p * 2; m = qs; }
  else { base = qkv + (size_t)s * QKV_LD + KOFF + (h - NH) * HD + p * 2; m = 1.f; }

  unsigned int both = *(const unsigned int*)base;
  float t0 = bf2f((unsigned short)(both & 0xffff));
  float t1 = bf2f((unsigned short)(both >> 16));
  unsigned int o0 = f2bf((t0 * c - t1 * sn) * m);
  unsigned int o1 = f2bf((t0 * sn + t1 * c) * m);
  *(unsigned int*)base = o0 | (o1 << 16);
}

// ---------------------------------------------------------------------------
// V transpose: vt[kv*HD + d][s] = qkv[s][VOFF + kv*HD + d]. (bf16)
// 32x32 LDS-tiled so both sides are coalesced.
// ---------------------------------------------------------------------------
__global__ __launch_bounds__(256) void vtrans_kernel(
    const unsigned short* __restrict__ qkv, unsigned short* __restrict__ vt)
{
  __shared__ unsigned short t[32][34];
  const int s0 = blockIdx.x * 32;                  // S_LEN/32 blocks
  const int d0 = blockIdx.y * 32;                  // (NKV*HD)/32 blocks
  const int tx = threadIdx.x & 31, ty = threadIdx.x >> 5;   // ty 0..7
#pragma unroll
  for (int i = 0; i < 32; i += 8)
    t[ty + i][tx] = qkv[(size_t)(s0 + ty + i) * QKV_LD + VOFF + d0 + tx];
  __syncthreads();
#pragma unroll
  for (int i = 0; i < 32; i += 8)
    vt[(size_t)(d0 + ty + i) * S_LEN + s0 + tx] = t[tx][ty + i];
}

// ---------------------------------------------------------------------------
// Flash attention, no-max softmax. Swapped QK^T (mfma(K,Q)) -> P lane-local,
// softmax in-register, PV A-frag via cross-quad shfl. Double-buffered K/V,
// one barrier per KV-iteration. Grid (NH, S/128); 4 waves; 2 blocks/CU.
// (verified round 3: 567 us total, attn no longer in top-5)
// ---------------------------------------------------------------------------
__global__ __launch_bounds__(256, 2) void attn_kernel(
    const unsigned short* __restrict__ qkv,
    const unsigned short* __restrict__ vt,
    unsigned short* __restrict__ o)
{
  __shared__ __align__(16) unsigned short Ks[2][64 * 136];
  __shared__ __align__(16) unsigned short Vs[2][128 * 72];

  const int h    = blockIdx.x;
  const int qblk = blockIdx.y;
  const int kvh  = h >> 2;
  const int tid  = threadIdx.x;
  const int lane = tid & 63;
  const int quad = lane >> 4;
  const int l16  = lane & 15;
  const int wave = tid >> 6;
  const int qr   = qblk * 128 + wave * 16;        // + mt*64

  bf16x8 qf[2][4];
#pragma unroll
  for (int mt = 0; mt < 2; mt++)
#pragma unroll
    for (int ks = 0; ks < 4; ks++)
      qf[mt][ks] = *(const bf16x8*)(qkv + (size_t)(qr + mt * 64 + l16) * QKV_LD
                                    + h * HD + ks * 32 + quad * 8);

  floatx4 accO[2][8] = {};
  float l_i[2] = {0.f, 0.f};

  int4 pk[4], pv4[4];
#define LOAD_TILE(kb_) do {                                                     \
    _Pragma("unroll")                                                           \
    for (int j = 0; j < 4; j++) {                                               \
      int c = tid + 256 * j;                                                    \
      pk[j] = *(const int4*)(qkv + (size_t)((kb_) * 64 + (c >> 4)) * QKV_LD     \
                              + KOFF + kvh * HD + (c & 15) * 8);                \
      pv4[j] = *(const int4*)(vt + (size_t)(kvh * HD + (c >> 3)) * S_LEN        \
                              + (kb_) * 64 + (c & 7) * 8);                      \
    } } while (0)
#define STORE_TILE(b_) do {                                                     \
    _Pragma("unroll")                                                           \
    for (int j = 0; j < 4; j++) {                                               \
      int c = tid + 256 * j;                                                    \
      *(int4*)(Ks[b_] + (c >> 4) * 136 + (c & 15) * 8) = pk[j];                 \
      *(int4*)(Vs[b_] + (c >> 3) * 72 + (c & 7) * 8) = pv4[j];                  \
    } } while (0)

  LOAD_TILE(0);
  STORE_TILE(0);
  __syncthreads();

  const int srcA = ((quad & 1) << 5) | l16;       // quad-pair source lane
  const bool hi  = (quad & 2);                    // nt = 2*k2 + (quad>>1)

  for (int kb = 0; kb < S_LEN / 64; kb++) {
    const int cur = kb & 1;
    if (kb + 1 < S_LEN / 64) LOAD_TILE(kb + 1);   // global->reg, spans compute

    const unsigned short* Ksc = Ks[cur];
    const unsigned short* Vsc = Vs[cur];

    // ---- S^T = K Q^T : lane holds P-row slice for q=l16 ----
    floatx4 sacc[2][4] = {};
    __builtin_amdgcn_s_setprio(1);
#pragma unroll
    for (int ks = 0; ks < 4; ks++)
#pragma unroll
      for (int nt = 0; nt < 4; nt++) {
        bf16x8 kf = *(const bf16x8*)(Ksc + (nt * 16 + l16) * 136 + ks * 32 + quad * 8);
        sacc[0][nt] = mfma16(kf, qf[0][ks], sacc[0][nt]);
        sacc[1][nt] = mfma16(kf, qf[1][ks], sacc[1][nt]);
      }
    __builtin_amdgcn_s_setprio(0);

    // ---- P = exp(S); per-lane l partial; pack to bf16 words in-register ----
    unsigned int wp[2][2][4];   // [mt][word 0/1][nt]
#pragma unroll
    for (int mt = 0; mt < 2; mt++) {
      float ls = 0.f;
#pragma unroll
      for (int nt = 0; nt < 4; nt++) {
        float e0 = __expf(sacc[mt][nt][0]);
        float e1 = __expf(sacc[mt][nt][1]);
        float e2 = __expf(sacc[mt][nt][2]);
        float e3 = __expf(sacc[mt][nt][3]);
        ls += (e0 + e1) + (e2 + e3);
        wp[mt][0][nt] = (unsigned int)f2bf(e0) | ((unsigned int)f2bf(e1) << 16);
        wp[mt][1][nt] = (unsigned int)f2bf(e2) | ((unsigned int)f2bf(e3) << 16);
      }
      l_i[mt] += ls;
    }

    // ---- O += P V ; A-fragment via cross-quad exchange ----
#pragma unroll
    for (int k2 = 0; k2 < 2; k2++) {
      bf16x8 paf[2];
#pragma unroll
      for (int mt = 0; mt < 2; mt++) {
        const int ntl = k2 * 2, nth = k2 * 2 + 1;
        unsigned int a0 = __shfl((int)wp[mt][0][ntl], srcA, 64);
        unsigned int b0 = __shfl((int)wp[mt][0][nth], srcA, 64);
        unsigned int a1 = __shfl((int)wp[mt][1][ntl], srcA, 64);
        unsigned int b1 = __shfl((int)wp[mt][1][nth], srcA, 64);
        unsigned int a2 = __shfl((int)wp[mt][0][ntl], srcA + 16, 64);
        unsigned int b2 = __shfl((int)wp[mt][0][nth], srcA + 16, 64);
        unsigned int a3 = __shfl((int)wp[mt][1][ntl], srcA + 16, 64);
        unsigned int b3 = __shfl((int)wp[mt][1][nth], srcA + 16, 64);
        U32x4 pw;
        pw.u[0] = hi ? b0 : a0;
        pw.u[1] = hi ? b1 : a1;
        pw.u[2] = hi ? b2 : a2;
        pw.u[3] = hi ? b3 : a3;
        paf[mt] = pw.v;
      }
      __builtin_amdgcn_s_setprio(1);
#pragma unroll
      for (int dt = 0; dt < 8; dt++) {
        bf16x8 vf = *(const bf16x8*)(Vsc + (dt * 16 + l16) * 72 + k2 * 32 + quad * 8);
        accO[0][dt] = mfma16(paf[0], vf, accO[0][dt]);
        accO[1][dt] = mfma16(paf[1], vf, accO[1][dt]);
      }
      __builtin_amdgcn_s_setprio(0);
    }

    if (kb + 1 < S_LEN / 64) STORE_TILE(cur ^ 1);   // buf was drained last iter
    __syncthreads();
  }

  // ---- l: sum the 4 quad partials for each q=l16; broadcast to output rows --
#pragma unroll
  for (int mt = 0; mt < 2; mt++) {
    l_i[mt] += __shfl_xor(l_i[mt], 16, 64);
    l_i[mt] += __shfl_xor(l_i[mt], 32, 64);
  }

#pragma unroll
  for (int mt = 0; mt < 2; mt++) {
    float lq[4];
#pragma unroll
    for (int i = 0; i < 4; i++) lq[i] = __shfl(l_i[mt], quad * 4 + i, 64);
#pragma unroll
    for (int dt = 0; dt < 8; dt++)
#pragma unroll
      for (int i = 0; i < 4; i++) {
        float val = accO[mt][dt][i] / lq[i];
        o[(size_t)(qr + mt * 64 + quad * 4 + i) * (NH * HD) + h * HD + dt * 16 + l16]
            = f2bf(val);
      }
  }
#undef LOAD_TILE
#undef STORE_TILE
}

// ---------------------------------------------------------------------------
extern "C" void kernel_launch(void* const* d_in, const int* in_sizes, int n_in,
                              void* d_out, int out_size, void* d_ws, size_t ws_size,
                              hipStream_t stream)
{
  const float* x    = (const float*)d_in[0];
  const float* fcos = (const float*)d_in[1];
  const float* fsin = (const float*)d_in[2];
  const float* wq   = (const float*)d_in[3];
  const float* wk   = (const float*)d_in[4];
  const float* wv   = (const float*)d_in[5];
  const float* wo   = (const float*)d_in[6];
  float* out = (float*)d_out;

  unsigned short* ws = (unsigned short*)d_ws;
  unsigned short* xb   = ws;                                   // S*DIM
  unsigned short* wT   = xb   + (size_t)S_LEN * DIM;           // [6144][4096]
  unsigned short* woT  = wT   + (size_t)QKV_LD * DIM;          // [4096][4096]
  unsigned short* qkv  = woT  + (size_t)DIM * (NH * HD);       // [S][6144]
  unsigned short* vt   = qkv  + (size_t)S_LEN * QKV_LD;        // [NKV][HD][S]
  unsigned short* attn = vt   + (size_t)S_LEN * (NKV * HD);    // [S][4096]
  // total ~146 MB of d_ws

  // one-time per launch: x -> bf16; weights -> bf16 [N][K], q|k|v contiguous
  cvt_f32_bf16<<<(S_LEN * DIM) / (256 * 8), 256, 0, stream>>>(x, xb);
  transpose_cvt<<<dim3(DIM / 32, DIM / 32),        256, 0, stream>>>(wq, wT, DIM, DIM);
  transpose_cvt<<<dim3((NKV * HD) / 32, DIM / 32), 256, 0, stream>>>(wk, wT + (size_t)KOFF * DIM, DIM, NKV * HD);
  transpose_cvt<<<dim3((NKV * HD) / 32, DIM / 32), 256, 0, stream>>>(wv, wT + (size_t)VOFF * DIM, DIM, NKV * HD);
  transpose_cvt<<<dim3(DIM / 32, (NH * HD) / 32),  256, 0, stream>>>(wo, woT, NH * HD, DIM);

  // fused QKV projection: [S][6144], 8-phase 256x256 -> grid (24, 8)
  gemm8<false>
      <<<dim3(QKV_LD / 256, S_LEN / 256), 512, 0, stream>>>(xb, wT, qkv, S_LEN, QKV_LD, DIM);

  rope_kernel<<<(S_LEN * (NH + NKV) * 64) / 256, 256, 0, stream>>>(qkv, fcos, fsin);
  vtrans_kernel<<<dim3(S_LEN / 32, (NKV * HD) / 32), 256, 0, stream>>>(qkv, vt);

  attn_kernel<<<dim3(NH, S_LEN / 128), 256, 0, stream>>>(qkv, vt, attn);

  // output projection -> fp32 d_out (m97 structure, known-good)
  gemm_bt<true><<<dim3(DIM / 128, S_LEN / 128), 256, 0, stream>>>(attn, woT, out, S_LEN, DIM, NH * HD);
}